// Round 1
// baseline (1384.335 us; speedup 1.0000x reference)
//
#include <hip/hip_runtime.h>
#include <hip/hip_bf16.h>
#include <stdint.h>

typedef unsigned short u16;
typedef __bf16 bf16x8 __attribute__((ext_vector_type(8)));
typedef float f32x4 __attribute__((ext_vector_type(4)));

#define NWIN 4096
#define NTOK 49
#define CDIM 384
#define NHEAD 12
#define HD 32
#define MROWS (NWIN * NTOK)   // 200704
#define QKVN (3 * CDIM)       // 1152
#define SCALE 0.17677669529663689f

__device__ __forceinline__ u16 f2bf(float f) {
  uint32_t u = __float_as_uint(f);
  u += 0x7fff + ((u >> 16) & 1);   // RNE
  return (u16)(u >> 16);
}

__device__ __forceinline__ void gload_lds16(const void* g, void* l) {
  __builtin_amdgcn_global_load_lds(
      (const __attribute__((address_space(1))) unsigned int*)g,
      (__attribute__((address_space(3))) unsigned int*)l, 16, 0, 0);
}

// ---------------- prep kernels ----------------

__global__ __launch_bounds__(256) void cvt_x_kernel(const float* __restrict__ x,
                                                    u16* __restrict__ xb, int n4) {
  int i = blockIdx.x * blockDim.x + threadIdx.x;
  int stride = gridDim.x * blockDim.x;
  for (; i < n4; i += stride) {
    float4 v = ((const float4*)x)[i];
    ushort4 o;
    o.x = f2bf(v.x); o.y = f2bf(v.y); o.z = f2bf(v.z); o.w = f2bf(v.w);
    ((ushort4*)xb)[i] = o;
  }
}

// w[K][N] (f32) -> wT[N][K] (bf16)
__global__ __launch_bounds__(256) void cvt_wT_kernel(const float* __restrict__ w,
                                                     u16* __restrict__ wT, int K, int N) {
  int i = blockIdx.x * blockDim.x + threadIdx.x;
  if (i >= K * N) return;
  int n = i / K, k = i - n * K;
  wT[i] = f2bf(w[k * N + n]);
}

// bias12p[12][64][64] = bias_table[rel_index]+mask, zero-padded to 64x64
__global__ __launch_bounds__(256) void build_bias_kernel(const float* __restrict__ bt,
                                                         const int* __restrict__ ri,
                                                         const float* __restrict__ mask,
                                                         float* __restrict__ bias12p) {
  int i = blockIdx.x * blockDim.x + threadIdx.x;
  if (i >= NHEAD * 64 * 64) return;
  int h = i >> 12, r = (i >> 6) & 63, c = i & 63;
  float v = 0.f;
  if (r < NTOK && c < NTOK) v = bt[ri[r * NTOK + c] * NHEAD + h] + mask[r * NTOK + c];
  bias12p[i] = v;
}

// ---------------- 128x128 bf16 MFMA GEMM (m97-style, single-buffered) ----------------
// A [M][K] bf16 row-major, BT [N][K] bf16 row-major. K % 64 == 0, M % 128 == 0, N % 128 == 0.
// MODE 0: QKV epilogue (scatter q/k/vT, q scaled). MODE 1: f32 out + bias.

template <int MODE>
__global__ __launch_bounds__(256) void gemm128(const u16* __restrict__ A,
                                               const u16* __restrict__ BT,
                                               const float* __restrict__ bias,
                                               float* __restrict__ outF,
                                               u16* __restrict__ q_ws,
                                               u16* __restrict__ k_ws,
                                               u16* __restrict__ vT_ws,
                                               int K, int n_tiles) {
  __shared__ __align__(16) u16 As[128 * 64];
  __shared__ __align__(16) u16 Bs[128 * 64];
  const int tid = threadIdx.x;
  const int wave = tid >> 6, lane = tid & 63;
  const int mt = blockIdx.x / n_tiles, nt = blockIdx.x % n_tiles;
  const int m0 = mt << 7, n0 = nt << 7;
  const int fr = lane & 15, fg = lane >> 4;
  const int wr = (wave >> 1) << 6, wc = (wave & 1) << 6;

  f32x4 acc[4][4] = {};

  for (int k0 = 0; k0 < K; k0 += 64) {
#pragma unroll
    for (int it = 0; it < 4; ++it) {
      const int c = it * 256 + tid;
      const int row = c >> 3, col8 = c & 7;
      gload_lds16(A + (size_t)(m0 + row) * K + k0 + col8 * 8, &As[c * 8]);
    }
#pragma unroll
    for (int it = 0; it < 4; ++it) {
      const int c = it * 256 + tid;
      const int row = c >> 3, col8 = c & 7;
      gload_lds16(BT + (size_t)(n0 + row) * K + k0 + col8 * 8, &Bs[c * 8]);
    }
    asm volatile("s_waitcnt vmcnt(0)" ::: "memory");
    __syncthreads();
#pragma unroll
    for (int kk = 0; kk < 2; ++kk) {
      bf16x8 av[4], bv[4];
#pragma unroll
      for (int i = 0; i < 4; ++i)
        av[i] = *(const bf16x8*)&As[(wr + i * 16 + fr) * 64 + kk * 32 + fg * 8];
#pragma unroll
      for (int i = 0; i < 4; ++i)
        bv[i] = *(const bf16x8*)&Bs[(wc + i * 16 + fr) * 64 + kk * 32 + fg * 8];
#pragma unroll
      for (int i = 0; i < 4; ++i)
#pragma unroll
        for (int j = 0; j < 4; ++j)
          acc[i][j] = __builtin_amdgcn_mfma_f32_16x16x32_bf16(av[i], bv[j], acc[i][j], 0, 0, 0);
    }
    __syncthreads();
  }

#pragma unroll
  for (int j = 0; j < 4; ++j) {
    const int col_g = n0 + wc + j * 16 + fr;
    const float bvadd = bias[col_g];
    if (MODE == 0) {
      const int s = col_g / CDIM;           // 0=q 1=k 2=v, uniform per block
      const int cr = col_g - s * CDIM;
      const int h = cr >> 5, d = cr & 31;
#pragma unroll
      for (int i = 0; i < 4; ++i) {
#pragma unroll
        for (int r = 0; r < 4; ++r) {
          const int row_g = m0 + wr + i * 16 + fg * 4 + r;
          const int b = row_g / NTOK, n = row_g - b * NTOK;
          const float v = acc[i][j][r] + bvadd;
          const size_t bh = (size_t)b * NHEAD + h;
          if (s == 0)      q_ws[(bh * NTOK + n) * HD + d] = f2bf(v * SCALE);
          else if (s == 1) k_ws[(bh * NTOK + n) * HD + d] = f2bf(v);
          else             vT_ws[(bh * HD + d) * 64 + n] = f2bf(v);
        }
      }
    } else {
#pragma unroll
      for (int i = 0; i < 4; ++i) {
#pragma unroll
        for (int r = 0; r < 4; ++r) {
          const int row_g = m0 + wr + i * 16 + fg * 4 + r;
          outF[(size_t)row_g * CDIM + col_g] = acc[i][j][r] + bvadd;
        }
      }
    }
  }
}

// ---------------- attention: one wave per (window, head) ----------------

__global__ __launch_bounds__(64) void attn_kernel(const u16* __restrict__ q_ws,
                                                  const u16* __restrict__ k_ws,
                                                  const u16* __restrict__ vT_ws,
                                                  const float* __restrict__ bias12p,
                                                  u16* __restrict__ att_ws) {
  __shared__ __align__(16) float S[64 * 68];
  __shared__ __align__(16) u16 P[64 * 72];
  const int bh = blockIdx.x;
  const int b = bh / NHEAD, h = bh - b * NHEAD;
  const int lane = threadIdx.x;
  const int fr = lane & 15, fg = lane >> 4;
  const u16* qp = q_ws + (size_t)bh * NTOK * HD;
  const u16* kp = k_ws + (size_t)bh * NTOK * HD;
  const u16* vp = vT_ws + (size_t)bh * HD * 64;

  // QK^T: S[64][64] (rows/cols >=49 are clamped duplicates, masked later)
  bf16x8 aq[4], bk[4];
#pragma unroll
  for (int i = 0; i < 4; ++i) {
    int m = i * 16 + fr;
    m = m < NTOK ? m : NTOK - 1;
    aq[i] = *(const bf16x8*)&qp[m * HD + fg * 8];
    bk[i] = *(const bf16x8*)&kp[m * HD + fg * 8];
  }
  f32x4 sacc[4][4] = {};
#pragma unroll
  for (int i = 0; i < 4; ++i)
#pragma unroll
    for (int j = 0; j < 4; ++j)
      sacc[i][j] = __builtin_amdgcn_mfma_f32_16x16x32_bf16(aq[i], bk[j], sacc[i][j], 0, 0, 0);

  const float* bp = bias12p + h * 64 * 64;
#pragma unroll
  for (int i = 0; i < 4; ++i)
#pragma unroll
    for (int j = 0; j < 4; ++j)
#pragma unroll
      for (int r = 0; r < 4; ++r) {
        const int row = i * 16 + fg * 4 + r, col = j * 16 + fr;
        S[row * 68 + col] = sacc[i][j][r] + bp[row * 64 + col];
      }
  __syncthreads();

  // softmax: lane = row (rows fully parallel across 64 lanes)
  {
    const int r = lane;
    if (r < NTOK) {
      float mx = -1e30f;
      for (int j = 0; j < NTOK; ++j) mx = fmaxf(mx, S[r * 68 + j]);
      float sum = 0.f;
      for (int j = 0; j < NTOK; ++j) {
        float e = __expf(S[r * 68 + j] - mx);
        sum += e;
        S[r * 68 + j] = e;
      }
      const float inv = 1.f / sum;
      for (int j = 0; j < NTOK; ++j) P[r * 72 + j] = f2bf(S[r * 68 + j] * inv);
      for (int j = NTOK; j < 64; ++j) P[r * 72 + j] = 0;  // zero pad cols: kills 0xAA vT pad
    } else {
      for (int j = 0; j < 64; ++j) P[r * 72 + j] = 0;      // zero pad rows
    }
  }
  __syncthreads();

  // PV: O[49][32] = P[64][64] @ v[64][32]  (B from vT[32][64], contiguous along k)
  f32x4 oacc[4][2] = {};
#pragma unroll
  for (int kt = 0; kt < 2; ++kt) {
    bf16x8 ap[4], bv[2];
#pragma unroll
    for (int i = 0; i < 4; ++i)
      ap[i] = *(const bf16x8*)&P[(i * 16 + fr) * 72 + kt * 32 + fg * 8];
#pragma unroll
    for (int n2 = 0; n2 < 2; ++n2)
      bv[n2] = *(const bf16x8*)&vp[(n2 * 16 + fr) * 64 + kt * 32 + fg * 8];
#pragma unroll
    for (int i = 0; i < 4; ++i)
#pragma unroll
      for (int n2 = 0; n2 < 2; ++n2)
        oacc[i][n2] = __builtin_amdgcn_mfma_f32_16x16x32_bf16(ap[i], bv[n2], oacc[i][n2], 0, 0, 0);
  }
  u16* ao = att_ws + ((size_t)b * NTOK) * CDIM + h * HD;
#pragma unroll
  for (int i = 0; i < 4; ++i)
#pragma unroll
    for (int n2 = 0; n2 < 2; ++n2)
#pragma unroll
      for (int r = 0; r < 4; ++r) {
        const int row = i * 16 + fg * 4 + r, col = n2 * 16 + fr;
        if (row < NTOK) ao[(size_t)row * CDIM + col] = f2bf(oacc[i][n2][r]);
      }
}

// ---------------- launch ----------------

extern "C" void kernel_launch(void* const* d_in, const int* in_sizes, int n_in,
                              void* d_out, int out_size, void* d_ws, size_t ws_size,
                              hipStream_t stream) {
  (void)in_sizes; (void)n_in; (void)out_size; (void)ws_size;
  const float* x      = (const float*)d_in[0];
  const float* mask   = (const float*)d_in[1];
  const float* qkv_w  = (const float*)d_in[2];
  const float* qkv_b  = (const float*)d_in[3];
  const float* proj_w = (const float*)d_in[4];
  const float* proj_b = (const float*)d_in[5];
  const float* btab   = (const float*)d_in[6];
  const int*   ridx   = (const int*)d_in[7];
  float* out = (float*)d_out;

  char* ws = (char*)d_ws;
  size_t off = 0;
  auto alloc = [&](size_t bytes) {
    char* p = ws + off;
    off = (off + bytes + 255) & ~(size_t)255;
    return p;
  };
  u16* q_ws    = (u16*)alloc((size_t)NWIN * NHEAD * NTOK * HD * 2);  // 154 MB
  u16* k_ws    = (u16*)alloc((size_t)NWIN * NHEAD * NTOK * HD * 2);  // 154 MB
  u16* vT_ws   = (u16*)alloc((size_t)NWIN * NHEAD * HD * 64 * 2);    // 201 MB (n padded to 64)
  u16* att_ws  = (u16*)alloc((size_t)MROWS * CDIM * 2);              // 154 MB
  u16* qkvWT   = (u16*)alloc((size_t)QKVN * CDIM * 2);
  u16* projWT  = (u16*)alloc((size_t)CDIM * CDIM * 2);
  float* bias12p = (float*)alloc((size_t)NHEAD * 64 * 64 * 4);

  u16* x_bf = (u16*)d_out;  // scratch: x in bf16 lives in d_out until final GEMM overwrites it

  cvt_x_kernel<<<4096, 256, 0, stream>>>(x, x_bf, MROWS * CDIM / 4);
  cvt_wT_kernel<<<(QKVN * CDIM + 255) / 256, 256, 0, stream>>>(qkv_w, qkvWT, CDIM, QKVN);
  cvt_wT_kernel<<<(CDIM * CDIM + 255) / 256, 256, 0, stream>>>(proj_w, projWT, CDIM, CDIM);
  build_bias_kernel<<<(NHEAD * 64 * 64 + 255) / 256, 256, 0, stream>>>(btab, ridx, mask, bias12p);

  gemm128<0><<<(MROWS / 128) * (QKVN / 128), 256, 0, stream>>>(
      x_bf, qkvWT, qkv_b, nullptr, q_ws, k_ws, vT_ws, CDIM, QKVN / 128);

  attn_kernel<<<NWIN * NHEAD, 64, 0, stream>>>(q_ws, k_ws, vT_ws, bias12p, att_ws);

  gemm128<1><<<(MROWS / 128) * (CDIM / 128), 256, 0, stream>>>(
      att_ws, projWT, proj_b, out, nullptr, nullptr, nullptr, CDIM, CDIM / 128);
}

// Round 6
// 1316.686 us; speedup vs baseline: 1.0514x; 1.0514x over previous
//
#include <hip/hip_runtime.h>
#include <hip/hip_bf16.h>
#include <stdint.h>

typedef unsigned short u16;
typedef __bf16 bf16x8 __attribute__((ext_vector_type(8)));
typedef float f32x4 __attribute__((ext_vector_type(4)));

#define NWIN 4096
#define NTOK 49
#define CDIM 384
#define NHEAD 12
#define HD 32
#define MROWS (NWIN * NTOK)   // 200704
#define QKVN (3 * CDIM)       // 1152
#define SCALE 0.17677669529663689f

__device__ __forceinline__ u16 f2bf(float f) {
  uint32_t u = __float_as_uint(f);
  u += 0x7fff + ((u >> 16) & 1);   // RNE
  return (u16)(u >> 16);
}

__device__ __forceinline__ void gload_lds16(const void* g, void* l) {
  __builtin_amdgcn_global_load_lds(
      (const __attribute__((address_space(1))) unsigned int*)g,
      (__attribute__((address_space(3))) unsigned int*)l, 16, 0, 0);
}

// ---------------- prep kernels ----------------

__global__ __launch_bounds__(256) void cvt_x_kernel(const float* __restrict__ x,
                                                    u16* __restrict__ xb, int n4) {
  int i = blockIdx.x * blockDim.x + threadIdx.x;
  int stride = gridDim.x * blockDim.x;
  for (; i < n4; i += stride) {
    float4 v = ((const float4*)x)[i];
    ushort4 o;
    o.x = f2bf(v.x); o.y = f2bf(v.y); o.z = f2bf(v.z); o.w = f2bf(v.w);
    ((ushort4*)xb)[i] = o;
  }
}

// w[K][N] (f32) -> wT[N][K] (bf16)
__global__ __launch_bounds__(256) void cvt_wT_kernel(const float* __restrict__ w,
                                                     u16* __restrict__ wT, int K, int N) {
  int i = blockIdx.x * blockDim.x + threadIdx.x;
  if (i >= K * N) return;
  int n = i / K, k = i - n * K;
  wT[i] = f2bf(w[k * N + n]);
}

// bias12p[12][64][64] = bias_table[rel_index]+mask, zero-padded to 64x64
__global__ __launch_bounds__(256) void build_bias_kernel(const float* __restrict__ bt,
                                                         const int* __restrict__ ri,
                                                         const float* __restrict__ mask,
                                                         float* __restrict__ bias12p) {
  int i = blockIdx.x * blockDim.x + threadIdx.x;
  if (i >= NHEAD * 64 * 64) return;
  int h = i >> 12, r = (i >> 6) & 63, c = i & 63;
  float v = 0.f;
  if (r < NTOK && c < NTOK) v = bt[ri[r * NTOK + c] * NHEAD + h] + mask[r * NTOK + c];
  bias12p[i] = v;
}

// ---------------- 128x128 bf16 MFMA GEMM ----------------
// Double-buffered (T3-minimum), T2 pre-swizzled LDS, XCD-chunked block swizzle.
// A [M][K] bf16 row-major, BT [N][K] bf16 row-major. K%64==0, M%128==0, N%128==0.
// Grid size must be divisible by 8 (it is: 14112 / 4704).
// MODE 0: QKV epilogue (scatter q/k/vT, q scaled). MODE 1: f32 out + bias.

template <int MODE>
__global__ __launch_bounds__(256) void gemm128(const u16* __restrict__ A,
                                               const u16* __restrict__ BT,
                                               const float* __restrict__ bias,
                                               float* __restrict__ outF,
                                               u16* __restrict__ q_ws,
                                               u16* __restrict__ k_ws,
                                               u16* __restrict__ vT_ws,
                                               int K, int n_tiles) {
  __shared__ __align__(16) u16 As[2][128 * 64];
  __shared__ __align__(16) u16 Bs[2][128 * 64];
  const int tid = threadIdx.x;
  const int wave = tid >> 6, lane = tid & 63;

  // XCD-chunked bijective swizzle: blocks on one XCD get consecutive tile ids
  const int nwg = gridDim.x;
  int bid = blockIdx.x;
  bid = (bid & 7) * (nwg >> 3) + (bid >> 3);

  const int mt = bid / n_tiles, ntile = bid - mt * n_tiles;
  const int m0 = mt << 7, n0 = ntile << 7;
  const int fr = lane & 15, fg = lane >> 4;
  const int wr = (wave >> 1) << 6, wc = (wave & 1) << 6;

  // per-thread staging coords (constant across iterations)
  // chunk c in [0,1024): row = c>>3, col8 = c&7, source col pre-swizzled (T2 / rule #21)
  f32x4 acc[4][4] = {};

  auto stage = [&](int k0s, int bufi) {
#pragma unroll
    for (int it = 0; it < 4; ++it) {
      const int c = it * 256 + tid;
      const int row = c >> 3, col8 = c & 7;
      const int scol = ((col8 ^ (row & 7)) << 3);
      gload_lds16(A + (size_t)(m0 + row) * K + k0s + scol, &As[bufi][c * 8]);
    }
#pragma unroll
    for (int it = 0; it < 4; ++it) {
      const int c = it * 256 + tid;
      const int row = c >> 3, col8 = c & 7;
      const int scol = ((col8 ^ (row & 7)) << 3);
      gload_lds16(BT + (size_t)(n0 + row) * K + k0s + scol, &Bs[bufi][c * 8]);
    }
  };

  const int nt = K >> 6;
  int cur = 0;

  stage(0, 0);
  __syncthreads();   // drains vmcnt for each wave before barrier

  for (int t = 0; t < nt; ++t) {
    if (t + 1 < nt) stage((t + 1) << 6, cur ^ 1);

#pragma unroll
    for (int kk = 0; kk < 2; ++kk) {
      bf16x8 av[4], bv[4];
#pragma unroll
      for (int i = 0; i < 4; ++i) {
        const int row = wr + i * 16 + fr;
        const int swz = ((kk << 2) | fg) ^ (fr & 7);   // row&7 == fr&7 (wr, i*16 are multiples of 8)
        av[i] = *(const bf16x8*)((const char*)&As[cur][0] + (size_t)row * 128 + (swz << 4));
      }
#pragma unroll
      for (int i = 0; i < 4; ++i) {
        const int row = wc + i * 16 + fr;
        const int swz = ((kk << 2) | fg) ^ (fr & 7);
        bv[i] = *(const bf16x8*)((const char*)&Bs[cur][0] + (size_t)row * 128 + (swz << 4));
      }
      __builtin_amdgcn_s_setprio(1);
#pragma unroll
      for (int i = 0; i < 4; ++i)
#pragma unroll
        for (int j = 0; j < 4; ++j)
          acc[i][j] = __builtin_amdgcn_mfma_f32_16x16x32_bf16(av[i], bv[j], acc[i][j], 0, 0, 0);
      __builtin_amdgcn_s_setprio(0);
    }

    if (t + 1 < nt) __syncthreads();
    cur ^= 1;
  }

#pragma unroll
  for (int j = 0; j < 4; ++j) {
    const int col_g = n0 + wc + j * 16 + fr;
    const float bvadd = bias[col_g];
    if (MODE == 0) {
      const int s = col_g / CDIM;           // 0=q 1=k 2=v, uniform per block
      const int cr = col_g - s * CDIM;
      const int h = cr >> 5, d = cr & 31;
#pragma unroll
      for (int i = 0; i < 4; ++i) {
#pragma unroll
        for (int r = 0; r < 4; ++r) {
          const int row_g = m0 + wr + i * 16 + fg * 4 + r;
          const int b = row_g / NTOK, n = row_g - b * NTOK;
          const float v = acc[i][j][r] + bvadd;
          const size_t bh = (size_t)b * NHEAD + h;
          if (s == 0)      q_ws[(bh * NTOK + n) * HD + d] = f2bf(v * SCALE);
          else if (s == 1) k_ws[(bh * NTOK + n) * HD + d] = f2bf(v);
          else             vT_ws[(bh * HD + d) * 64 + n] = f2bf(v);
        }
      }
    } else {
#pragma unroll
      for (int i = 0; i < 4; ++i) {
#pragma unroll
        for (int r = 0; r < 4; ++r) {
          const int row_g = m0 + wr + i * 16 + fg * 4 + r;
          outF[(size_t)row_g * CDIM + col_g] = acc[i][j][r] + bvadd;
        }
      }
    }
  }
}

// ---------------- attention: one wave per (window, head) ----------------

__global__ __launch_bounds__(64) void attn_kernel(const u16* __restrict__ q_ws,
                                                  const u16* __restrict__ k_ws,
                                                  const u16* __restrict__ vT_ws,
                                                  const float* __restrict__ bias12p,
                                                  u16* __restrict__ att_ws) {
  __shared__ __align__(16) float S[64 * 65];   // stride 65: (65r+j)%32 conflict-free both axes
  __shared__ __align__(16) u16 P[64 * 72];
  const int bh = blockIdx.x;
  const int b = bh / NHEAD, h = bh - b * NHEAD;
  const int lane = threadIdx.x;
  const int fr = lane & 15, fg = lane >> 4;
  const u16* qp = q_ws + (size_t)bh * NTOK * HD;
  const u16* kp = k_ws + (size_t)bh * NTOK * HD;
  const u16* vp = vT_ws + (size_t)bh * HD * 64;

  // QK^T: S[64][64] (rows/cols >=49 are clamped duplicates, masked later)
  bf16x8 aq[4], bk[4];
#pragma unroll
  for (int i = 0; i < 4; ++i) {
    int m = i * 16 + fr;
    m = m < NTOK ? m : NTOK - 1;
    aq[i] = *(const bf16x8*)&qp[m * HD + fg * 8];
    bk[i] = *(const bf16x8*)&kp[m * HD + fg * 8];
  }
  f32x4 sacc[4][4] = {};
#pragma unroll
  for (int i = 0; i < 4; ++i)
#pragma unroll
    for (int j = 0; j < 4; ++j)
      sacc[i][j] = __builtin_amdgcn_mfma_f32_16x16x32_bf16(aq[i], bk[j], sacc[i][j], 0, 0, 0);

  const float* bp = bias12p + h * 64 * 64;
#pragma unroll
  for (int i = 0; i < 4; ++i)
#pragma unroll
    for (int j = 0; j < 4; ++j)
#pragma unroll
      for (int r = 0; r < 4; ++r) {
        const int row = i * 16 + fg * 4 + r, col = j * 16 + fr;
        S[row * 65 + col] = sacc[i][j][r] + bp[row * 64 + col];
      }
  __syncthreads();

  // softmax: lane = row (rows fully parallel across 64 lanes)
  {
    const int r = lane;
    if (r < NTOK) {
      float mx = -1e30f;
      for (int j = 0; j < NTOK; ++j) mx = fmaxf(mx, S[r * 65 + j]);
      float sum = 0.f;
      for (int j = 0; j < NTOK; ++j) {
        float e = __expf(S[r * 65 + j] - mx);
        sum += e;
        S[r * 65 + j] = e;
      }
      const float inv = 1.f / sum;
      for (int j = 0; j < NTOK; ++j) P[r * 72 + j] = f2bf(S[r * 65 + j] * inv);
      for (int j = NTOK; j < 64; ++j) P[r * 72 + j] = 0;  // zero pad cols: kills 0xAA vT pad
    } else {
      for (int j = 0; j < 64; ++j) P[r * 72 + j] = 0;      // zero pad rows
    }
  }
  __syncthreads();

  // PV: O[49][32] = P[64][64] @ v[64][32]  (B from vT[32][64], contiguous along k)
  f32x4 oacc[4][2] = {};
#pragma unroll
  for (int kt = 0; kt < 2; ++kt) {
    bf16x8 ap[4], bv[2];
#pragma unroll
    for (int i = 0; i < 4; ++i)
      ap[i] = *(const bf16x8*)&P[(i * 16 + fr) * 72 + kt * 32 + fg * 8];
#pragma unroll
    for (int n2 = 0; n2 < 2; ++n2)
      bv[n2] = *(const bf16x8*)&vp[(n2 * 16 + fr) * 64 + kt * 32 + fg * 8];
#pragma unroll
    for (int i = 0; i < 4; ++i)
#pragma unroll
      for (int n2 = 0; n2 < 2; ++n2)
        oacc[i][n2] = __builtin_amdgcn_mfma_f32_16x16x32_bf16(ap[i], bv[n2], oacc[i][n2], 0, 0, 0);
  }
  u16* ao = att_ws + ((size_t)b * NTOK) * CDIM + h * HD;
#pragma unroll
  for (int i = 0; i < 4; ++i)
#pragma unroll
    for (int n2 = 0; n2 < 2; ++n2)
#pragma unroll
      for (int r = 0; r < 4; ++r) {
        const int row = i * 16 + fg * 4 + r, col = n2 * 16 + fr;
        if (row < NTOK) ao[(size_t)row * CDIM + col] = f2bf(oacc[i][n2][r]);
      }
}

// ---------------- launch ----------------

extern "C" void kernel_launch(void* const* d_in, const int* in_sizes, int n_in,
                              void* d_out, int out_size, void* d_ws, size_t ws_size,
                              hipStream_t stream) {
  (void)in_sizes; (void)n_in; (void)out_size; (void)ws_size;
  const float* x      = (const float*)d_in[0];
  const float* mask   = (const float*)d_in[1];
  const float* qkv_w  = (const float*)d_in[2];
  const float* qkv_b  = (const float*)d_in[3];
  const float* proj_w = (const float*)d_in[4];
  const float* proj_b = (const float*)d_in[5];
  const float* btab   = (const float*)d_in[6];
  const int*   ridx   = (const int*)d_in[7];
  float* out = (float*)d_out;

  char* ws = (char*)d_ws;
  size_t off = 0;
  auto alloc = [&](size_t bytes) {
    char* p = ws + off;
    off = (off + bytes + 255) & ~(size_t)255;
    return p;
  };
  u16* q_ws    = (u16*)alloc((size_t)NWIN * NHEAD * NTOK * HD * 2);  // 154 MB
  u16* k_ws    = (u16*)alloc((size_t)NWIN * NHEAD * NTOK * HD * 2);  // 154 MB
  u16* vT_ws   = (u16*)alloc((size_t)NWIN * NHEAD * HD * 64 * 2);    // 201 MB (n padded to 64)
  u16* att_ws  = (u16*)alloc((size_t)MROWS * CDIM * 2);              // 154 MB
  u16* qkvWT   = (u16*)alloc((size_t)QKVN * CDIM * 2);
  u16* projWT  = (u16*)alloc((size_t)CDIM * CDIM * 2);
  float* bias12p = (float*)alloc((size_t)NHEAD * 64 * 64 * 4);

  u16* x_bf = (u16*)d_out;  // scratch: x in bf16 lives in d_out until final GEMM overwrites it

  cvt_x_kernel<<<4096, 256, 0, stream>>>(x, x_bf, MROWS * CDIM / 4);
  cvt_wT_kernel<<<(QKVN * CDIM + 255) / 256, 256, 0, stream>>>(qkv_w, qkvWT, CDIM, QKVN);
  cvt_wT_kernel<<<(CDIM * CDIM + 255) / 256, 256, 0, stream>>>(proj_w, projWT, CDIM, CDIM);
  build_bias_kernel<<<(NHEAD * 64 * 64 + 255) / 256, 256, 0, stream>>>(btab, ridx, mask, bias12p);

  gemm128<0><<<(MROWS / 128) * (QKVN / 128), 256, 0, stream>>>(
      x_bf, qkvWT, qkv_b, nullptr, q_ws, k_ws, vT_ws, CDIM, QKVN / 128);

  attn_kernel<<<NWIN * NHEAD, 64, 0, stream>>>(q_ws, k_ws, vT_ws, bias12p, att_ws);

  gemm128<1><<<(MROWS / 128) * (CDIM / 128), 256, 0, stream>>>(
      att_ws, projWT, proj_b, out, nullptr, nullptr, nullptr, CDIM, CDIM / 128);
}

// Round 7
// 1252.934 us; speedup vs baseline: 1.1049x; 1.0509x over previous
//
#include <hip/hip_runtime.h>
#include <hip/hip_bf16.h>
#include <stdint.h>

typedef unsigned short u16;
typedef __bf16 bf16x8 __attribute__((ext_vector_type(8)));
typedef float f32x4 __attribute__((ext_vector_type(4)));

#define NWIN 4096
#define NTOK 49
#define CDIM 384
#define NHEAD 12
#define HD 32
#define MROWS (NWIN * NTOK)   // 200704
#define QKVN (3 * CDIM)       // 1152
#define GK 384                // K of both GEMMs (compile-time)
#define GNT 6                 // GK / 64
#define SCALE 0.17677669529663689f

__device__ __forceinline__ u16 f2bf(float f) {
  uint32_t u = __float_as_uint(f);
  u += 0x7fff + ((u >> 16) & 1);   // RNE
  return (u16)(u >> 16);
}

__device__ __forceinline__ void gload_lds16(const void* g, void* l) {
  __builtin_amdgcn_global_load_lds(
      (const __attribute__((address_space(1))) unsigned int*)g,
      (__attribute__((address_space(3))) unsigned int*)l, 16, 0, 0);
}

// ---------------- prep kernels ----------------

__global__ __launch_bounds__(256) void cvt_x_kernel(const float* __restrict__ x,
                                                    u16* __restrict__ xb, int n4) {
  int i = blockIdx.x * blockDim.x + threadIdx.x;
  int stride = gridDim.x * blockDim.x;
  for (; i < n4; i += stride) {
    float4 v = ((const float4*)x)[i];
    ushort4 o;
    o.x = f2bf(v.x); o.y = f2bf(v.y); o.z = f2bf(v.z); o.w = f2bf(v.w);
    ((ushort4*)xb)[i] = o;
  }
}

// w[K][N] (f32) -> wT[N][K] (bf16)
__global__ __launch_bounds__(256) void cvt_wT_kernel(const float* __restrict__ w,
                                                     u16* __restrict__ wT, int K, int N) {
  int i = blockIdx.x * blockDim.x + threadIdx.x;
  if (i >= K * N) return;
  int n = i / K, k = i - n * K;
  wT[i] = f2bf(w[k * N + n]);
}

// bias12p[12][64][64] = bias_table[rel_index]+mask, zero-padded to 64x64
__global__ __launch_bounds__(256) void build_bias_kernel(const float* __restrict__ bt,
                                                         const int* __restrict__ ri,
                                                         const float* __restrict__ mask,
                                                         float* __restrict__ bias12p) {
  int i = blockIdx.x * blockDim.x + threadIdx.x;
  if (i >= NHEAD * 64 * 64) return;
  int h = i >> 12, r = (i >> 6) & 63, c = i & 63;
  float v = 0.f;
  if (r < NTOK && c < NTOK) v = bt[ri[r * NTOK + c] * NHEAD + h] + mask[r * NTOK + c];
  bias12p[i] = v;
}

// ---------------- 128x128 bf16 MFMA GEMM ----------------
// Depth-2 counted-vmcnt pipeline (T4): tiles t, t+1 in flight; vmcnt(8) per iter
// (vmcnt(0) only on the last tile). Two raw s_barriers per iter, no full drain.
// T2 pre-swizzled LDS (both-sides involution), XCD-chunked block swizzle.
// A [M][GK] bf16 row-major, BT [N][GK] bf16 row-major.
// MODE 0: QKV epilogue (scatter q/k/vT, q scaled). MODE 1: f32 out + bias.

template <int MODE>
__global__ __launch_bounds__(256) void gemm128(const u16* __restrict__ A,
                                               const u16* __restrict__ BT,
                                               const float* __restrict__ bias,
                                               float* __restrict__ outF,
                                               u16* __restrict__ q_ws,
                                               u16* __restrict__ k_ws,
                                               u16* __restrict__ vT_ws,
                                               int n_tiles) {
  __shared__ __align__(16) u16 As[2][128 * 64];
  __shared__ __align__(16) u16 Bs[2][128 * 64];
  const int tid = threadIdx.x;
  const int wave = tid >> 6, lane = tid & 63;

  // XCD-chunked bijective swizzle (grid % 8 == 0)
  const int nwg = gridDim.x;
  int bid = blockIdx.x;
  bid = (bid & 7) * (nwg >> 3) + (bid >> 3);

  const int mt = bid / n_tiles, ntile = bid - mt * n_tiles;
  const int m0 = mt << 7, n0 = ntile << 7;
  const int fr = lane & 15, fg = lane >> 4;
  const int wr = (wave >> 1) << 6, wc = (wave & 1) << 6;

  f32x4 acc[4][4] = {};

  // chunk c in [0,1024): row=c>>3, col8=c&7, source col pre-swizzled (rule #21)
  auto stage = [&](int k0s, int bufi) {
#pragma unroll
    for (int it = 0; it < 4; ++it) {
      const int c = it * 256 + tid;
      const int row = c >> 3, col8 = c & 7;
      const int scol = ((col8 ^ (row & 7)) << 3);
      gload_lds16(A + (size_t)(m0 + row) * GK + k0s + scol, &As[bufi][c * 8]);
    }
#pragma unroll
    for (int it = 0; it < 4; ++it) {
      const int c = it * 256 + tid;
      const int row = c >> 3, col8 = c & 7;
      const int scol = ((col8 ^ (row & 7)) << 3);
      gload_lds16(BT + (size_t)(n0 + row) * GK + k0s + scol, &Bs[bufi][c * 8]);
    }
  };

  stage(0, 0);    // 8 loads: tile 0
  stage(64, 1);   // 8 loads: tile 1  (16 outstanding)

#pragma unroll
  for (int t = 0; t < GNT; ++t) {
    // wait for tile t only: 8 loads (tile t+1) may remain in flight
    if (t < GNT - 1) asm volatile("s_waitcnt vmcnt(8)" ::: "memory");
    else             asm volatile("s_waitcnt vmcnt(0)" ::: "memory");
    __builtin_amdgcn_s_barrier();

    const int buf = t & 1;
#pragma unroll
    for (int kk = 0; kk < 2; ++kk) {
      bf16x8 av[4], bv[4];
#pragma unroll
      for (int i = 0; i < 4; ++i) {
        const int row = wr + i * 16 + fr;
        const int swz = ((kk << 2) | fg) ^ (fr & 7);   // row&7 == fr&7 here
        av[i] = *(const bf16x8*)((const char*)&As[buf][0] + (size_t)row * 128 + (swz << 4));
      }
#pragma unroll
      for (int i = 0; i < 4; ++i) {
        const int row = wc + i * 16 + fr;
        const int swz = ((kk << 2) | fg) ^ (fr & 7);
        bv[i] = *(const bf16x8*)((const char*)&Bs[buf][0] + (size_t)row * 128 + (swz << 4));
      }
      __builtin_amdgcn_s_setprio(1);
#pragma unroll
      for (int i = 0; i < 4; ++i)
#pragma unroll
        for (int j = 0; j < 4; ++j)
          acc[i][j] = __builtin_amdgcn_mfma_f32_16x16x32_bf16(av[i], bv[j], acc[i][j], 0, 0, 0);
      __builtin_amdgcn_s_setprio(0);
    }

    // all waves done reading buf -> safe to DMA-overwrite it with tile t+2
    __builtin_amdgcn_s_barrier();
    if (t + 2 < GNT) stage((t + 2) << 6, buf);
  }

  // ---------------- epilogue ----------------
  const int col0 = n0 + wc + fr;
  float bvadd[4];
#pragma unroll
  for (int j = 0; j < 4; ++j) bvadd[j] = bias[col0 + j * 16];

  if (MODE == 0) {
    const int s = col0 / CDIM;   // wave-uniform (64-col span never straddles 384)
    int hh[4], dd[4];
#pragma unroll
    for (int j = 0; j < 4; ++j) {
      const int cr = col0 + j * 16 - s * CDIM;
      hh[j] = cr >> 5; dd[j] = cr & 31;
    }
#pragma unroll
    for (int i = 0; i < 4; ++i) {
#pragma unroll
      for (int r = 0; r < 4; ++r) {
        const int row_g = m0 + wr + i * 16 + fg * 4 + r;
        const int b = row_g / NTOK, n = row_g - b * NTOK;   // once per row
        const size_t bhb = (size_t)b * NHEAD;
#pragma unroll
        for (int j = 0; j < 4; ++j) {
          const float v = acc[i][j][r] + bvadd[j];
          const size_t bh = bhb + hh[j];
          if (s == 0)      q_ws[(bh * NTOK + n) * HD + dd[j]] = f2bf(v * SCALE);
          else if (s == 1) k_ws[(bh * NTOK + n) * HD + dd[j]] = f2bf(v);
          else             vT_ws[(bh * HD + dd[j]) * 64 + n] = f2bf(v);
        }
      }
    }
  } else {
#pragma unroll
    for (int i = 0; i < 4; ++i) {
#pragma unroll
      for (int r = 0; r < 4; ++r) {
        const int row_g = m0 + wr + i * 16 + fg * 4 + r;
        float* op = outF + (size_t)row_g * CDIM + col0;
#pragma unroll
        for (int j = 0; j < 4; ++j) op[j * 16] = acc[i][j][r] + bvadd[j];
      }
    }
  }
}

// ---------------- attention: one wave per (window, head) ----------------
// v2: V prefetched to regs before QK^T; single-pass register softmax
// (row read once, stride-66 S conflict-free both axes); branch-free pad-row
// zeroing via inv*(r<49); P packed in regs, written as 8x ds_write_b128.

__global__ __launch_bounds__(64) void attn_kernel(const u16* __restrict__ q_ws,
                                                  const u16* __restrict__ k_ws,
                                                  const u16* __restrict__ vT_ws,
                                                  const float* __restrict__ bias12p,
                                                  u16* __restrict__ att_ws) {
  __shared__ __align__(16) float S[64 * 66];   // stride 66: writes 2-way, reads 2-way (free)
  __shared__ __align__(16) u16 P[64 * 72];     // stride 144B: even bank tiling for b128
  const int bh = blockIdx.x;
  const int b = bh / NHEAD, h = bh - b * NHEAD;
  const int lane = threadIdx.x;
  const int fr = lane & 15, fg = lane >> 4;
  const u16* qp = q_ws + (size_t)bh * NTOK * HD;
  const u16* kp = k_ws + (size_t)bh * NTOK * HD;
  const u16* vp = vT_ws + (size_t)bh * HD * 64;

  // --- prefetch V fragments early (independent of everything before PV) ---
  bf16x8 bv[2][2];
#pragma unroll
  for (int kt = 0; kt < 2; ++kt)
#pragma unroll
    for (int n2 = 0; n2 < 2; ++n2)
      bv[kt][n2] = *(const bf16x8*)&vp[(n2 * 16 + fr) * 64 + kt * 32 + fg * 8];

  // --- QK^T ---
  bf16x8 aq[4], bk[4];
#pragma unroll
  for (int i = 0; i < 4; ++i) {
    int m = i * 16 + fr;
    m = m < NTOK ? m : NTOK - 1;           // clamped duplicate rows, masked later
    aq[i] = *(const bf16x8*)&qp[m * HD + fg * 8];
    bk[i] = *(const bf16x8*)&kp[m * HD + fg * 8];
  }
  f32x4 sacc[4][4] = {};
#pragma unroll
  for (int i = 0; i < 4; ++i)
#pragma unroll
    for (int j = 0; j < 4; ++j)
      sacc[i][j] = __builtin_amdgcn_mfma_f32_16x16x32_bf16(aq[i], bk[j], sacc[i][j], 0, 0, 0);

  const float* bp = bias12p + h * 64 * 64;
#pragma unroll
  for (int i = 0; i < 4; ++i)
#pragma unroll
    for (int j = 0; j < 4; ++j)
#pragma unroll
      for (int r = 0; r < 4; ++r) {
        const int row = i * 16 + fg * 4 + r, col = j * 16 + fr;
        S[row * 66 + col] = sacc[i][j][r] + bp[row * 64 + col];
      }
  __syncthreads();

  // --- single-pass softmax: lane = row ---
  {
    const int r = lane;
    float sv[49];
#pragma unroll
    for (int j = 0; j < 49; ++j) sv[j] = S[r * 66 + j];
    float mx = sv[0];
#pragma unroll
    for (int j = 1; j < 49; ++j) mx = fmaxf(mx, sv[j]);
    float s0 = 0.f, s1 = 0.f;
#pragma unroll
    for (int j = 0; j < 48; j += 2) {
      sv[j]     = __expf(sv[j] - mx);     s0 += sv[j];
      sv[j + 1] = __expf(sv[j + 1] - mx); s1 += sv[j + 1];
    }
    sv[48] = __expf(sv[48] - mx); s0 += sv[48];
    const float inv = (r < NTOK) ? 1.f / (s0 + s1) : 0.f;  // zeroes pad rows, branch-free
#pragma unroll
    for (int c = 0; c < 8; ++c) {
      uint32_t w[4];
#pragma unroll
      for (int u = 0; u < 4; ++u) {
        const int j0 = c * 8 + u * 2, j1 = j0 + 1;
        const uint32_t lo = (j0 < 49) ? (uint32_t)f2bf(sv[j0] * inv) : 0u;
        const uint32_t hi = (j1 < 49) ? (uint32_t)f2bf(sv[j1] * inv) : 0u;
        w[u] = lo | (hi << 16);
      }
      *(uint4*)&P[r * 72 + c * 8] = make_uint4(w[0], w[1], w[2], w[3]);
    }
  }
  __syncthreads();

  // --- PV: O[49][32] = P[64][64] @ v[64][32] (B fragments already in regs) ---
  f32x4 oacc[4][2] = {};
#pragma unroll
  for (int kt = 0; kt < 2; ++kt) {
    bf16x8 ap[4];
#pragma unroll
    for (int i = 0; i < 4; ++i)
      ap[i] = *(const bf16x8*)&P[(i * 16 + fr) * 72 + kt * 32 + fg * 8];
#pragma unroll
    for (int i = 0; i < 4; ++i)
#pragma unroll
      for (int n2 = 0; n2 < 2; ++n2)
        oacc[i][n2] = __builtin_amdgcn_mfma_f32_16x16x32_bf16(ap[i], bv[kt][n2], oacc[i][n2], 0, 0, 0);
  }
  u16* ao = att_ws + ((size_t)b * NTOK) * CDIM + h * HD;
#pragma unroll
  for (int i = 0; i < 4; ++i)
#pragma unroll
    for (int n2 = 0; n2 < 2; ++n2)
#pragma unroll
      for (int r = 0; r < 4; ++r) {
        const int row = i * 16 + fg * 4 + r, col = n2 * 16 + fr;
        if (row < NTOK) ao[(size_t)row * CDIM + col] = f2bf(oacc[i][n2][r]);
      }
}

// ---------------- launch ----------------

extern "C" void kernel_launch(void* const* d_in, const int* in_sizes, int n_in,
                              void* d_out, int out_size, void* d_ws, size_t ws_size,
                              hipStream_t stream) {
  (void)in_sizes; (void)n_in; (void)out_size; (void)ws_size;
  const float* x      = (const float*)d_in[0];
  const float* mask   = (const float*)d_in[1];
  const float* qkv_w  = (const float*)d_in[2];
  const float* qkv_b  = (const float*)d_in[3];
  const float* proj_w = (const float*)d_in[4];
  const float* proj_b = (const float*)d_in[5];
  const float* btab   = (const float*)d_in[6];
  const int*   ridx   = (const int*)d_in[7];
  float* out = (float*)d_out;

  char* ws = (char*)d_ws;
  size_t off = 0;
  auto alloc = [&](size_t bytes) {
    char* p = ws + off;
    off = (off + bytes + 255) & ~(size_t)255;
    return p;
  };
  u16* q_ws    = (u16*)alloc((size_t)NWIN * NHEAD * NTOK * HD * 2);  // 154 MB
  u16* k_ws    = (u16*)alloc((size_t)NWIN * NHEAD * NTOK * HD * 2);  // 154 MB
  u16* vT_ws   = (u16*)alloc((size_t)NWIN * NHEAD * HD * 64 * 2);    // 201 MB (n padded to 64)
  u16* att_ws  = (u16*)alloc((size_t)MROWS * CDIM * 2);              // 154 MB
  u16* qkvWT   = (u16*)alloc((size_t)QKVN * CDIM * 2);
  u16* projWT  = (u16*)alloc((size_t)CDIM * CDIM * 2);
  float* bias12p = (float*)alloc((size_t)NHEAD * 64 * 64 * 4);

  u16* x_bf = (u16*)d_out;  // scratch: x in bf16 lives in d_out until final GEMM overwrites it

  cvt_x_kernel<<<4096, 256, 0, stream>>>(x, x_bf, MROWS * CDIM / 4);
  cvt_wT_kernel<<<(QKVN * CDIM + 255) / 256, 256, 0, stream>>>(qkv_w, qkvWT, CDIM, QKVN);
  cvt_wT_kernel<<<(CDIM * CDIM + 255) / 256, 256, 0, stream>>>(proj_w, projWT, CDIM, CDIM);
  build_bias_kernel<<<(NHEAD * 64 * 64 + 255) / 256, 256, 0, stream>>>(btab, ridx, mask, bias12p);

  gemm128<0><<<(MROWS / 128) * (QKVN / 128), 256, 0, stream>>>(
      x_bf, qkvWT, qkv_b, nullptr, q_ws, k_ws, vT_ws, QKVN / 128);

  attn_kernel<<<NWIN * NHEAD, 64, 0, stream>>>(q_ws, k_ws, vT_ws, bias12p, att_ws);

  gemm128<1><<<(MROWS / 128) * (CDIM / 128), 256, 0, stream>>>(
      att_ws, projWT, proj_b, out, nullptr, nullptr, nullptr, CDIM / 128);
}